// Round 4
// baseline (131.729 us; speedup 1.0000x reference)
//
#include <hip/hip_runtime.h>

// Problem constants
#define B_   16
#define C_   512
#define N_   1024   // H*W
#define F_   1024
#define T_   180
#define G_   32

// Workspace layout (float offsets). Total = 65536 + 524288 floats ~= 2.36 MB.
#define WS_MU    0                    // 512  (B*G)
#define WS_RSIG  512                  // 512
#define WS_K     1024                 // 16384 (B*F)
#define WS_V     (1024 + 16384)       // 16384
#define WS_WQS   (1024 + 2*16384)     // 512   WQsum[c] = sum_o wq[o,c]
#define WS_WOS   (WS_WQS + 512)       // 512   WOsum[o] = sum_c wo[o,c]
#define WS_BQS   (WS_WOS + 512)       // 4     BQsum
#define WS_POFF  (WS_BQS + 4)         // 512   per-(b,g) offset partials
#define WS_A     (WS_POFF + 512)      // 16384 A[b,n] attention output scalar per n
#define WS_P     65536                // B*G*N = 524288: P[b,g,n] = sum_{c in g} x*gamma*wqs

// ---------------------------------------------------------------------------
// Kernel 1 (k_w): weight-only reductions + K/V projections. Fully parallel.
//   blocks [0,16)  : WQsum for 32-c chunk
//   blocks [16,32) : WOsum for 32 o-rows (row sums, float4)
//   blocks [32,96) : K[b,f], V[b,f] — float4 over t (180 = 45*4)
//   block  96      : BQsum
// ---------------------------------------------------------------------------
__global__ __launch_bounds__(256) void k_w(
    const float* __restrict__ cond,
    const float* __restrict__ wq, const float* __restrict__ bq,
    const float* __restrict__ wk, const float* __restrict__ bk,
    const float* __restrict__ wv, const float* __restrict__ bv,
    const float* __restrict__ wo, float* __restrict__ ws)
{
    const int blk = blockIdx.x;
    const int tid = threadIdx.x;

    if (blk < 16) {
        const int c0 = blk << 5;
        const int oi = tid >> 5;        // 0..7
        const int ci = tid & 31;
        float acc = 0.f;
        #pragma unroll 8
        for (int ob = 0; ob < 64; ++ob) {
            const int o = (ob << 3) + oi;
            acc += wq[o * C_ + c0 + ci];
        }
        __shared__ float part[8][32];
        part[oi][ci] = acc;
        __syncthreads();
        if (tid < 32) {
            float s = 0.f;
            #pragma unroll
            for (int j = 0; j < 8; ++j) s += part[j][tid];
            ws[WS_WQS + c0 + tid] = s;
        }
    } else if (blk < 32) {
        const int o0 = (blk - 16) << 5;
        const int r  = tid >> 3;        // 0..31
        const int j  = tid & 7;         // 0..7
        const float4* row = (const float4*)(wo + (size_t)(o0 + r) * C_);
        float acc = 0.f;
        #pragma unroll
        for (int jj = 0; jj < 16; ++jj) {
            float4 p = row[(jj << 3) + j];
            acc += (p.x + p.y) + (p.z + p.w);
        }
        #pragma unroll
        for (int off = 4; off; off >>= 1) acc += __shfl_down(acc, off, 8);
        if (j == 0) ws[WS_WOS + o0 + r] = acc;
    } else if (blk < 96) {
        const int idx = blk - 32;           // [0,64)
        const int b   = idx >> 2;
        const int f   = ((idx & 3) << 8) + tid;
        __shared__ __align__(16) float condl[T_];
        if (tid < T_) condl[tid] = cond[b * T_ + tid];
        __syncthreads();
        const float4* c4  = (const float4*)condl;
        const float4* wk4 = (const float4*)(wk + (size_t)f * T_);   // 720 B rows, 16B-aligned
        const float4* wv4 = (const float4*)(wv + (size_t)f * T_);
        float accK = bk[f];
        float accV = bv[f];
        #pragma unroll 5
        for (int t4 = 0; t4 < 45; ++t4) {
            float4 cf = c4[t4];
            float4 a  = wk4[t4];
            float4 vv = wv4[t4];
            accK = fmaf(cf.x, a.x,  fmaf(cf.y, a.y,  fmaf(cf.z, a.z,  fmaf(cf.w, a.w,  accK))));
            accV = fmaf(cf.x, vv.x, fmaf(cf.y, vv.y, fmaf(cf.z, vv.z, fmaf(cf.w, vv.w, accV))));
        }
        ws[WS_K + b * F_ + f] = accK;
        ws[WS_V + b * F_ + f] = accV;
    } else {
        float p = bq[tid] + bq[tid + 256];
        #pragma unroll
        for (int off = 32; off; off >>= 1) p += __shfl_down(p, off, 64);
        __shared__ float rb[4];
        if ((tid & 63) == 0) rb[tid >> 6] = p;
        __syncthreads();
        if (tid == 0) ws[WS_BQS] = rb[0] + rb[1] + rb[2] + rb[3];
    }
}

// ---------------------------------------------------------------------------
// Kernel 2 (k_stats): per (b,g) — ONE pass over the 64 KB x-slab computing
// mu/rsig, P[b,g,n], and the per-(b,g) offset partial.
// ---------------------------------------------------------------------------
__global__ __launch_bounds__(256) void k_stats(
    const float* __restrict__ x, const float* __restrict__ gamma,
    const float* __restrict__ beta, float* __restrict__ ws)
{
    const int blk = blockIdx.x;       // b*32+g
    const int g   = blk & 31;
    const int tid = threadIdx.x;

    __shared__ float wl[16], bwl[16];
    __shared__ float rs[4], rq[4];
    if (tid < 16) {
        const int c = (g << 4) + tid;
        const float wqs = ws[WS_WQS + c];
        wl[tid]  = gamma[c] * wqs;
        bwl[tid] = beta[c]  * wqs;
    }
    __syncthreads();

    const float4* xv = (const float4*)(x + (size_t)blk * 16384);
    float4 p4 = make_float4(0.f, 0.f, 0.f, 0.f);
    float s = 0.f, sq = 0.f;
    #pragma unroll
    for (int j = 0; j < 16; ++j) {        // j == local channel
        float4 p = xv[tid + (j << 8)];
        s  += (p.x + p.y) + (p.z + p.w);
        sq += p.x * p.x + p.y * p.y + p.z * p.z + p.w * p.w;
        const float wj = wl[j];
        p4.x = fmaf(p.x, wj, p4.x);
        p4.y = fmaf(p.y, wj, p4.y);
        p4.z = fmaf(p.z, wj, p4.z);
        p4.w = fmaf(p.w, wj, p4.w);
    }
    *(float4*)(ws + WS_P + (size_t)blk * 1024 + (tid << 2)) = p4;

    #pragma unroll
    for (int off = 32; off; off >>= 1) {
        s  += __shfl_down(s,  off, 64);
        sq += __shfl_down(sq, off, 64);
    }
    if ((tid & 63) == 0) { rs[tid >> 6] = s; rq[tid >> 6] = sq; }
    __syncthreads();
    if (tid == 0) {
        const float S1 = rs[0] + rs[1] + rs[2] + rs[3];
        const float S2 = rq[0] + rq[1] + rq[2] + rq[3];
        const float mu  = S1 * (1.f / 16384.f);
        const float var = S2 * (1.f / 16384.f) - mu * mu;
        const float rsig = rsqrtf(var + 1e-6f);
        ws[WS_MU   + blk] = mu;
        ws[WS_RSIG + blk] = rsig;
        float sw = 0.f, sbw = 0.f;
        #pragma unroll
        for (int j = 0; j < 16; ++j) { sw += wl[j]; sbw += bwl[j]; }
        ws[WS_POFF + blk] = sbw - mu * rsig * sw;
    }
}

// ---------------------------------------------------------------------------
// Kernel 3 (k_attn): per (b, 32-n tile): S -> rank-1 softmax -> A[b,n] in ws.
// Grid: 512 blocks = 16 b x 32 n-tiles; 256 threads. (Phases A-C of old k_fused.)
// ---------------------------------------------------------------------------
__global__ __launch_bounds__(256) void k_attn(
    const float* __restrict__ ws_in, float* __restrict__ ws)
{
    const float* wsr = ws_in;
    const int b   = blockIdx.x >> 5;
    const int n0  = (blockIdx.x & 31) << 5;
    const int tid = threadIdx.x;

    __shared__ __align__(16) float KV[2 * F_];   // interleaved {K,V} pairs
    __shared__ float rsigl[32];
    __shared__ float part[8][32];
    __shared__ float pse[8][32], psv[8][32];
    __shared__ float Sl[32];
    __shared__ float redmx[4], redmn[4];
    __shared__ float opw;

    // ---- Phase A: rsig + offset partials + K/V staging + K extrema ----
    if (tid < 32) rsigl[tid] = wsr[WS_RSIG + (b << 5) + tid];
    float op = (tid < 32) ? wsr[WS_POFF + (b << 5) + tid] : 0.f;

    const float* Kg = wsr + WS_K + b * F_;
    const float* Vg = wsr + WS_V + b * F_;
    float mx = -1e30f, mn = 1e30f;
    float2* KV2 = (float2*)KV;
    #pragma unroll
    for (int i = tid; i < F_; i += 256) {
        float kv = Kg[i];
        KV2[i] = make_float2(kv, Vg[i]);    // ds_write_b64
        mx = fmaxf(mx, kv);
        mn = fminf(mn, kv);
    }
    #pragma unroll
    for (int off = 32; off; off >>= 1) {
        op += __shfl_down(op, off, 64);
        mx = fmaxf(mx, __shfl_down(mx, off, 64));
        mn = fminf(mn, __shfl_down(mn, off, 64));
    }
    if ((tid & 63) == 0) {
        redmx[tid >> 6] = mx;
        redmn[tid >> 6] = mn;
        if (tid == 0) opw = op + wsr[WS_BQS];
    }
    __syncthreads();
    const float offset = opw;
    const float maxK = fmaxf(fmaxf(redmx[0], redmx[1]), fmaxf(redmx[2], redmx[3]));
    const float minK = fminf(fminf(redmn[0], redmn[1]), fminf(redmn[2], redmn[3]));

    // ---- Phase B: S over the tile from P (coalesced) ----
    const int nl = tid & 31;
    const int gq = tid >> 5;              // 0..7, 4 groups each
    {
        const float* Pp = wsr + WS_P + ((size_t)((b << 5) + (gq << 2)) << 10) + n0 + nl;
        float acc = 0.f;
        #pragma unroll
        for (int j = 0; j < 4; ++j)
            acc = fmaf(rsigl[(gq << 2) + j], Pp[(size_t)j << 10], acc);
        part[gq][nl] = acc;
    }
    __syncthreads();
    if (tid < 32) {
        float s8 = 0.f;
        #pragma unroll
        for (int j = 0; j < 8; ++j) s8 += part[j][tid];
        Sl[tid] = s8 + offset;
    }
    __syncthreads();

    // ---- Phase C: rank-1 softmax over f (float2 LDS reads, broadcast) ----
    const float LOG2E = 1.4426950408889634f;
    const float scale = 0.044194173824159216f;   // 512^-0.5
    const float s  = Sl[nl] * scale;
    const float sl = s * LOG2E;
    const float ml = (s >= 0.f ? maxK : minK) * sl;   // log2-domain row max

    float se = 0.f, sv = 0.f;
    const int fq = tid >> 5;              // 0..7, 128 f each
    const int fbase = fq << 7;
    #pragma unroll 8
    for (int fi = 0; fi < 128; ++fi) {
        float2 kv = KV2[fbase + fi];      // ds_read_b64, same addr across 32 lanes
        float e = exp2f(fmaf(sl, kv.x, -ml));
        se += e;
        sv = fmaf(kv.y, e, sv);
    }
    pse[fq][nl] = se;
    psv[fq][nl] = sv;
    __syncthreads();
    if (tid < 32) {
        float den = 0.f, num = 0.f;
        #pragma unroll
        for (int j = 0; j < 8; ++j) { den += pse[j][tid]; num += psv[j][tid]; }
        ws[WS_A + (b << 10) + n0 + tid] = num / den;
    }
}

// ---------------------------------------------------------------------------
// Kernel 4 (k_out): pure stream, out[b,o,n] = x[b,o,n] + A[b,n]*WOsum[o] + bo[o].
// Grid-stride over 2,097,152 float4s; 2048 blocks x 256 threads (4 iters).
// ---------------------------------------------------------------------------
__global__ __launch_bounds__(256) void k_out(
    const float* __restrict__ x, const float* __restrict__ bo,
    const float* __restrict__ ws, float* __restrict__ out)
{
    const int tot4 = B_ * C_ * (N_ / 4);           // 2,097,152
    const int stride = 2048 * 256;                 // 524,288
    int i4 = blockIdx.x * 256 + threadIdx.x;
    #pragma unroll 4
    for (int it = 0; it < 4; ++it, i4 += stride) {
        const int n4 = i4 & 255;                   // float4 index along n
        const int o  = (i4 >> 8) & 511;
        const int b  = i4 >> 17;
        const float4 a4 = *(const float4*)(ws + WS_A + (b << 10) + (n4 << 2));
        const float w   = ws[WS_WOS + o];
        const float bof = bo[o];
        const float4 xv = ((const float4*)x)[i4];
        float4 ov;
        ov.x = xv.x + fmaf(a4.x, w, bof);
        ov.y = xv.y + fmaf(a4.y, w, bof);
        ov.z = xv.z + fmaf(a4.z, w, bof);
        ov.w = xv.w + fmaf(a4.w, w, bof);
        ((float4*)out)[i4] = ov;
    }
}

extern "C" void kernel_launch(void* const* d_in, const int* in_sizes, int n_in,
                              void* d_out, int out_size, void* d_ws, size_t ws_size,
                              hipStream_t stream) {
    const float* x     = (const float*)d_in[0];
    const float* cond  = (const float*)d_in[1];
    const float* gamma = (const float*)d_in[2];
    const float* beta  = (const float*)d_in[3];
    const float* wq    = (const float*)d_in[4];
    const float* bq    = (const float*)d_in[5];
    const float* wk    = (const float*)d_in[6];
    const float* bk    = (const float*)d_in[7];
    const float* wv    = (const float*)d_in[8];
    const float* bv    = (const float*)d_in[9];
    const float* wo    = (const float*)d_in[10];
    const float* bo    = (const float*)d_in[11];
    float* ws  = (float*)d_ws;
    float* out = (float*)d_out;

    hipLaunchKernelGGL(k_w, dim3(97), dim3(256), 0, stream,
                       cond, wq, bq, wk, bk, wv, bv, wo, ws);
    hipLaunchKernelGGL(k_stats, dim3(512), dim3(256), 0, stream,
                       x, gamma, beta, ws);
    hipLaunchKernelGGL(k_attn, dim3(512), dim3(256), 0, stream,
                       ws, ws);
    hipLaunchKernelGGL(k_out, dim3(2048), dim3(256), 0, stream,
                       x, bo, ws, out);
}

// Round 6
// 124.793 us; speedup vs baseline: 1.0556x; 1.0556x over previous
//
#include <hip/hip_runtime.h>

// Problem constants
#define B_   16
#define C_   512
#define N_   1024   // H*W
#define F_   1024
#define T_   180
#define G_   32

// Workspace layout (float offsets). Total = 36864 + 524288 floats ~= 2.2 MB.
#define WS_MU    0                    // 512  (B*G)
#define WS_RSIG  512                  // 512
#define WS_K     1024                 // 16384 (B*F)
#define WS_V     (1024 + 16384)       // 16384
#define WS_WOS   (1024 + 2*16384)     // 512   WOsum[o] = sum_c wo[o,c]
#define WS_BQS   (WS_WOS + 512)       // 4     BQsum
#define WS_POFF  (WS_BQS + 4)         // 512   per-(b,g) offset partials
#define WS_P     36864                // B*G*N = 524288: P[b,g,n] = sum_{c in g} x*gamma*wqs

// ---------------------------------------------------------------------------
// Kernel 1 (k_prep) — single dispatch, 593 blocks:
//   blocks [0,512)   : per-(b,g) group stats + P + POFF. Each block redundantly
//                      computes its group's 16 WQsum columns (32 KB of wq,
//                      L2-resident) — removes the WQS cross-block dependency
//                      that forced a separate kernel. x-slab loads are issued
//                      into registers FIRST so they cover the wq gather latency.
//   blocks [512,576) : K[b,f], V[b,f] — float4 over t (180 = 45*4)
//   blocks [576,592) : WOsum for 32 o-rows each (row sums, float4)
//   block  592       : BQsum
// ---------------------------------------------------------------------------
__global__ __launch_bounds__(256) void k_prep(
    const float* __restrict__ x, const float* __restrict__ gamma,
    const float* __restrict__ beta, const float* __restrict__ cond,
    const float* __restrict__ wq, const float* __restrict__ bq,
    const float* __restrict__ wk, const float* __restrict__ bk,
    const float* __restrict__ wv, const float* __restrict__ bv,
    const float* __restrict__ wo, float* __restrict__ ws)
{
    const int blk = blockIdx.x;
    const int tid = threadIdx.x;

    if (blk < 512) {
        // ---- stats + P + POFF, with per-block redundant WQsum ----
        const int g  = blk & 31;
        const int c0 = g << 4;

        // Issue the 64 KB x-slab into registers first (latency cover).
        const float4* xv = (const float4*)(x + (size_t)blk * 16384);
        float4 xr[16];
        #pragma unroll
        for (int j = 0; j < 16; ++j) xr[j] = xv[tid + (j << 8)];

        // Redundant WQsum for this group's 16 channels: sum_o wq[o*512 + c0+j]
        __shared__ float wqpart[16][16];
        {
            const int j  = tid & 15;   // channel-in-group
            const int oi = tid >> 4;   // 0..15
            const float* wqp = wq + (size_t)oi * C_ + c0 + j;
            float a = 0.f;
            #pragma unroll 8
            for (int k = 0; k < 32; ++k)
                a += wqp[(size_t)(k << 4) * C_];   // o = oi + k*16
            wqpart[oi][j] = a;
        }
        __syncthreads();
        __shared__ float wl[16], bwl[16];
        if (tid < 16) {
            float wqs = 0.f;
            #pragma unroll
            for (int k = 0; k < 16; ++k) wqs += wqpart[k][tid];
            const int c = c0 + tid;
            wl[tid]  = gamma[c] * wqs;
            bwl[tid] = beta[c]  * wqs;
        }
        __syncthreads();

        float4 p4 = make_float4(0.f, 0.f, 0.f, 0.f);
        float s = 0.f, sq = 0.f;
        #pragma unroll
        for (int j = 0; j < 16; ++j) {        // j == local channel
            float4 p = xr[j];
            s  += (p.x + p.y) + (p.z + p.w);
            sq += p.x * p.x + p.y * p.y + p.z * p.z + p.w * p.w;
            const float wj = wl[j];
            p4.x = fmaf(p.x, wj, p4.x);
            p4.y = fmaf(p.y, wj, p4.y);
            p4.z = fmaf(p.z, wj, p4.z);
            p4.w = fmaf(p.w, wj, p4.w);
        }
        *(float4*)(ws + WS_P + (size_t)blk * 1024 + (tid << 2)) = p4;

        __shared__ float rs[4], rq[4];
        #pragma unroll
        for (int off = 32; off; off >>= 1) {
            s  += __shfl_down(s,  off, 64);
            sq += __shfl_down(sq, off, 64);
        }
        if ((tid & 63) == 0) { rs[tid >> 6] = s; rq[tid >> 6] = sq; }
        __syncthreads();
        if (tid == 0) {
            const float S1 = rs[0] + rs[1] + rs[2] + rs[3];
            const float S2 = rq[0] + rq[1] + rq[2] + rq[3];
            const float mu  = S1 * (1.f / 16384.f);
            const float var = S2 * (1.f / 16384.f) - mu * mu;
            const float rsig = rsqrtf(var + 1e-6f);
            ws[WS_MU   + blk] = mu;
            ws[WS_RSIG + blk] = rsig;
            float sw = 0.f, sbw = 0.f;
            #pragma unroll
            for (int j = 0; j < 16; ++j) { sw += wl[j]; sbw += bwl[j]; }
            ws[WS_POFF + blk] = sbw - mu * rsig * sw;
        }
    } else if (blk < 576) {
        // ---- K/V: one thread per f, float4 over t ----
        const int idx = blk - 512;          // [0,64)
        const int b   = idx >> 2;
        const int f   = ((idx & 3) << 8) + tid;
        __shared__ __align__(16) float condl[T_];
        if (tid < T_) condl[tid] = cond[b * T_ + tid];
        __syncthreads();
        const float4* c4  = (const float4*)condl;
        const float4* wk4 = (const float4*)(wk + (size_t)f * T_);   // 720 B rows, 16B-aligned
        const float4* wv4 = (const float4*)(wv + (size_t)f * T_);
        float accK = bk[f];
        float accV = bv[f];
        #pragma unroll 5
        for (int t4 = 0; t4 < 45; ++t4) {
            float4 cf = c4[t4];
            float4 a  = wk4[t4];
            float4 vv = wv4[t4];
            accK = fmaf(cf.x, a.x,  fmaf(cf.y, a.y,  fmaf(cf.z, a.z,  fmaf(cf.w, a.w,  accK))));
            accV = fmaf(cf.x, vv.x, fmaf(cf.y, vv.y, fmaf(cf.z, vv.z, fmaf(cf.w, vv.w, accV))));
        }
        ws[WS_K + b * F_ + f] = accK;
        ws[WS_V + b * F_ + f] = accV;
    } else if (blk < 592) {
        // ---- WOsum[o] = sum_c wo[o*512+c]; 32 rows per block, 8 lanes/row ----
        const int o0 = (blk - 576) << 5;
        const int r  = tid >> 3;        // 0..31
        const int j  = tid & 7;         // 0..7
        const float4* row = (const float4*)(wo + (size_t)(o0 + r) * C_);
        float acc = 0.f;
        #pragma unroll
        for (int jj = 0; jj < 16; ++jj) {
            float4 p = row[(jj << 3) + j];
            acc += (p.x + p.y) + (p.z + p.w);
        }
        #pragma unroll
        for (int off = 4; off; off >>= 1) acc += __shfl_down(acc, off, 8);
        if (j == 0) ws[WS_WOS + o0 + r] = acc;
    } else {
        // ---- BQsum ----
        float p = bq[tid] + bq[tid + 256];
        #pragma unroll
        for (int off = 32; off; off >>= 1) p += __shfl_down(p, off, 64);
        __shared__ float rb[4];
        if ((tid & 63) == 0) rb[tid >> 6] = p;
        __syncthreads();
        if (tid == 0) ws[WS_BQS] = rb[0] + rb[1] + rb[2] + rb[3];
    }
}

// ---------------------------------------------------------------------------
// Kernel 2 (k_fused): per (b, 32-n tile)  [identical to the measured 125.9 µs
// version]:
//   S[n]   = sum_g rsig[b,g]*P[b,g,n] + offset[b]
//   A[n]   = sum_f V[b,f]*softmax_f(scale*S[n]*K[b,f])   (analytic max: K extremum)
//   out[b,o,n] = x[b,o,n] + A[n]*WOsum[o] + bo[o]
// Grid: 512 blocks = 16 b x 32 n-tiles; 256 threads.
// ---------------------------------------------------------------------------
__global__ __launch_bounds__(256) void k_fused(
    const float* __restrict__ x, const float* __restrict__ bo,
    const float* __restrict__ ws, float* __restrict__ out)
{
    const int b   = blockIdx.x >> 5;
    const int n0  = (blockIdx.x & 31) << 5;
    const int tid = threadIdx.x;

    __shared__ __align__(16) float KV[2 * F_];   // interleaved {K,V} pairs
    __shared__ float rsigl[32];
    __shared__ float part[8][32];
    __shared__ float pse[8][32], psv[8][32];
    __shared__ float Sl[32], Al[32];
    __shared__ float redmx[4], redmn[4];
    __shared__ float opw;

    // ---- Phase A: rsig + offset partials + K/V staging + K extrema ----
    if (tid < 32) rsigl[tid] = ws[WS_RSIG + (b << 5) + tid];
    float op = (tid < 32) ? ws[WS_POFF + (b << 5) + tid] : 0.f;

    const float* Kg = ws + WS_K + b * F_;
    const float* Vg = ws + WS_V + b * F_;
    float mx = -1e30f, mn = 1e30f;
    float2* KV2 = (float2*)KV;
    #pragma unroll
    for (int i = tid; i < F_; i += 256) {
        float kv = Kg[i];
        KV2[i] = make_float2(kv, Vg[i]);    // ds_write_b64
        mx = fmaxf(mx, kv);
        mn = fminf(mn, kv);
    }
    #pragma unroll
    for (int off = 32; off; off >>= 1) {
        op += __shfl_down(op, off, 64);
        mx = fmaxf(mx, __shfl_down(mx, off, 64));
        mn = fminf(mn, __shfl_down(mn, off, 64));
    }
    if ((tid & 63) == 0) {
        redmx[tid >> 6] = mx;
        redmn[tid >> 6] = mn;
        if (tid == 0) opw = op + ws[WS_BQS];
    }
    __syncthreads();
    const float offset = opw;
    const float maxK = fmaxf(fmaxf(redmx[0], redmx[1]), fmaxf(redmx[2], redmx[3]));
    const float minK = fminf(fminf(redmn[0], redmn[1]), fminf(redmn[2], redmn[3]));

    // ---- Phase B: S over the tile from P (coalesced) ----
    const int nl = tid & 31;
    const int gq = tid >> 5;              // 0..7, 4 groups each
    {
        const float* Pp = ws + WS_P + ((size_t)((b << 5) + (gq << 2)) << 10) + n0 + nl;
        float acc = 0.f;
        #pragma unroll
        for (int j = 0; j < 4; ++j)
            acc = fmaf(rsigl[(gq << 2) + j], Pp[(size_t)j << 10], acc);
        part[gq][nl] = acc;
    }
    __syncthreads();
    if (tid < 32) {
        float s8 = 0.f;
        #pragma unroll
        for (int j = 0; j < 8; ++j) s8 += part[j][tid];
        Sl[tid] = s8 + offset;
    }
    __syncthreads();

    // ---- Phase C: rank-1 softmax over f (float2 LDS reads, broadcast) ----
    const float LOG2E = 1.4426950408889634f;
    const float scale = 0.044194173824159216f;   // 512^-0.5
    const float s  = Sl[nl] * scale;
    const float sl = s * LOG2E;
    const float ml = (s >= 0.f ? maxK : minK) * sl;   // log2-domain row max

    float se = 0.f, sv = 0.f;
    const int fq = tid >> 5;              // 0..7, 128 f each
    const int fbase = fq << 7;
    #pragma unroll 8
    for (int fi = 0; fi < 128; ++fi) {
        float2 kv = KV2[fbase + fi];      // ds_read_b64, same addr across 32 lanes
        float e = exp2f(fmaf(sl, kv.x, -ml));
        se += e;
        sv = fmaf(kv.y, e, sv);
    }
    pse[fq][nl] = se;
    psv[fq][nl] = sv;

    // ---- Hoisted Phase-D gathers: overlap with the Phase-C reduce ----
    const int col = tid & 7;    // n4-group: n-offset col*4
    const int row = tid >> 3;   // 0..31
    const float* WOS = ws + WS_WOS;
    float wv_[16], bo_[16];
    #pragma unroll
    for (int p = 0; p < 16; ++p) {
        wv_[p] = WOS[(p << 5) + row];
        bo_[p] = bo[(p << 5) + row];
    }

    __syncthreads();
    if (tid < 32) {
        float den = 0.f, num = 0.f;
        #pragma unroll
        for (int j = 0; j < 8; ++j) { den += pse[j][tid]; num += psv[j][tid]; }
        Al[tid] = num / den;
    }
    __syncthreads();

    // ---- Phase D: residual + projected-out write (float4 along n) ----
    float av[4];
    #pragma unroll
    for (int j = 0; j < 4; ++j) av[j] = Al[(col << 2) + j];

    #pragma unroll
    for (int p = 0; p < 16; ++p) {
        const int o = (p << 5) + row;
        const size_t base = (((size_t)(b * C_ + o)) << 10) + n0 + (col << 2);
        float4 xv = *(const float4*)(x + base);
        float4 ov;
        ov.x = xv.x + fmaf(av[0], wv_[p], bo_[p]);
        ov.y = xv.y + fmaf(av[1], wv_[p], bo_[p]);
        ov.z = xv.z + fmaf(av[2], wv_[p], bo_[p]);
        ov.w = xv.w + fmaf(av[3], wv_[p], bo_[p]);
        *(float4*)(out + base) = ov;
    }
}

extern "C" void kernel_launch(void* const* d_in, const int* in_sizes, int n_in,
                              void* d_out, int out_size, void* d_ws, size_t ws_size,
                              hipStream_t stream) {
    const float* x     = (const float*)d_in[0];
    const float* cond  = (const float*)d_in[1];
    const float* gamma = (const float*)d_in[2];
    const float* beta  = (const float*)d_in[3];
    const float* wq    = (const float*)d_in[4];
    const float* bq    = (const float*)d_in[5];
    const float* wk    = (const float*)d_in[6];
    const float* bk    = (const float*)d_in[7];
    const float* wv    = (const float*)d_in[8];
    const float* bv    = (const float*)d_in[9];
    const float* wo    = (const float*)d_in[10];
    const float* bo    = (const float*)d_in[11];
    float* ws  = (float*)d_ws;
    float* out = (float*)d_out;

    hipLaunchKernelGGL(k_prep, dim3(593), dim3(256), 0, stream,
                       x, gamma, beta, cond, wq, bq, wk, bk, wv, bv, wo, ws);
    hipLaunchKernelGGL(k_fused, dim3(512), dim3(256), 0, stream,
                       x, bo, ws, out);
}